// Round 1
// 181.178 us; speedup vs baseline: 1.0489x; 1.0489x over previous
//
#include <hip/hip_runtime.h>
#include <math.h>

// Problem constants (B hard-coded to 8, C==1, H=W=2048 per reference)
constexpr int HH   = 2048;
constexpr int WW   = 2048;
constexpr int BB   = 8;
constexpr unsigned NPB  = (unsigned)HH * (unsigned)WW;  // 4,194,304 elements/batch
constexpr unsigned NVEC = NPB / 4;                       // float4 per batch
constexpr int NBLK = 256;   // blocks per batch in pass 1
constexpr int TPB  = 256;
constexpr int WIN  = 5;     // 11x11 window half-width

typedef float f32x4 __attribute__((ext_vector_type(4)));

__device__ __forceinline__ void argmax_combine(float& bv, unsigned& bi,
                                               float ov, unsigned oi) {
    // strict > keeps first occurrence; tie -> smaller index (matches jnp.argmax)
    if (ov > bv || (ov == bv && oi < bi)) { bv = ov; bi = oi; }
}

// Pass 1: per-(batch, block) partials over ALL elements:
//   max + argmax, sum(max(x,0)), sum(max(x,0)^2), count(x>0)
__global__ __launch_bounds__(TPB) void psr_pass1(
    const float* __restrict__ resp,
    double* __restrict__ dS, double* __restrict__ dSS,
    float* __restrict__ fM, unsigned* __restrict__ uI,
    unsigned* __restrict__ uC)
{
    const int b = blockIdx.y;
    const f32x4* __restrict__ base =
        reinterpret_cast<const f32x4*>(resp) + (size_t)b * NVEC;
    const unsigned tid = blockIdx.x * TPB + threadIdx.x;

    float fsum = 0.f, fss = 0.f;
    float bv = -INFINITY;
    unsigned bi = 0, cnt = 0;

    #pragma unroll 4
    for (unsigned v = tid; v < NVEC; v += (unsigned)(NBLK * TPB)) {
        // streamed exactly once; skip cache allocation (poison fills thrash L2/L3 anyway)
        f32x4 x = __builtin_nontemporal_load(&base[v]);
        unsigned e0 = v * 4u;
        float r;
        r = fmaxf(x.x, 0.f); fsum += r; fss = fmaf(r, r, fss); cnt += (x.x > 0.f);
        if (x.x > bv) { bv = x.x; bi = e0; }
        r = fmaxf(x.y, 0.f); fsum += r; fss = fmaf(r, r, fss); cnt += (x.y > 0.f);
        if (x.y > bv) { bv = x.y; bi = e0 + 1u; }
        r = fmaxf(x.z, 0.f); fsum += r; fss = fmaf(r, r, fss); cnt += (x.z > 0.f);
        if (x.z > bv) { bv = x.z; bi = e0 + 2u; }
        r = fmaxf(x.w, 0.f); fsum += r; fss = fmaf(r, r, fss); cnt += (x.w > 0.f);
        if (x.w > bv) { bv = x.w; bi = e0 + 3u; }
    }

    double ds = (double)fsum, dss = (double)fss;
    // wave(64) reduce
    for (int off = 32; off > 0; off >>= 1) {
        ds  += __shfl_down(ds,  off, 64);
        dss += __shfl_down(dss, off, 64);
        cnt += __shfl_down(cnt, off, 64);
        float    ov = __shfl_down(bv, off, 64);
        unsigned oi = __shfl_down(bi, off, 64);
        argmax_combine(bv, bi, ov, oi);
    }

    __shared__ double sds[4], sdss[4];
    __shared__ float  sbv[4];
    __shared__ unsigned sbi[4], scnt[4];
    const int wave = threadIdx.x >> 6;
    const int lane = threadIdx.x & 63;
    if (lane == 0) {
        sds[wave] = ds; sdss[wave] = dss;
        sbv[wave] = bv; sbi[wave] = bi; scnt[wave] = cnt;
    }
    __syncthreads();
    if (threadIdx.x == 0) {
        for (int w = 1; w < 4; ++w) {
            ds += sds[w]; dss += sdss[w]; cnt += scnt[w];
            argmax_combine(bv, bi, sbv[w], sbi[w]);
        }
        const unsigned p = (unsigned)b * NBLK + blockIdx.x;
        dS[p] = ds; dSS[p] = dss; fM[p] = bv; uI[p] = bi; uC[p] = cnt;
    }
}

// Pass 2 (fused with old pass 3): ONE block, 8 waves, wave w handles batch w.
// Reduce 256 partials per batch, subtract the 11x11 window's positive
// contribution, compute psr[b] per wave, then thread 0 averages the 8 values
// in the exact pairwise order of the old shuffle tree (bit-exact vs before).
__global__ __launch_bounds__(512) void psr_pass2(
    const float* __restrict__ resp,
    const double* __restrict__ dS, const double* __restrict__ dSS,
    const float* __restrict__ fM, const unsigned* __restrict__ uI,
    const unsigned* __restrict__ uC,
    float* __restrict__ out)
{
    const int t    = threadIdx.x;
    const int wave = t >> 6;     // == batch index
    const int lane = t & 63;
    const int b    = wave;

    // ---- reduce the 256 partials of this batch across the wave ----
    double ds = 0.0, dss = 0.0;
    unsigned cnt = 0;
    float bv = -INFINITY;
    unsigned bi = 0u;
    #pragma unroll
    for (int k = lane; k < NBLK; k += 64) {
        const unsigned p = (unsigned)b * NBLK + (unsigned)k;
        ds  += dS[p];
        dss += dSS[p];
        cnt += uC[p];
        argmax_combine(bv, bi, fM[p], uI[p]);
    }
    for (int off = 32; off > 0; off >>= 1) {
        ds  += __shfl_down(ds,  off, 64);
        dss += __shfl_down(dss, off, 64);
        cnt += __shfl_down(cnt, off, 64);
        float    ov = __shfl_down(bv, off, 64);
        unsigned oi = __shfl_down(bi, off, 64);
        argmax_combine(bv, bi, ov, oi);
    }
    // broadcast the winning max/argmax to all lanes (sums stay valid on lane 0)
    bv = __shfl(bv, 0, 64);
    bi = __shfl(bi, 0, 64);

    // ---- window correction: 121 cells spread over the 64 lanes ----
    const int cy = (int)(bi >> 11);     // / 2048
    const int cx = (int)(bi & 2047u);   // % 2048

    double wsum = 0.0, wss = 0.0;
    unsigned wcnt = 0;
    #pragma unroll
    for (int c = lane; c < (2 * WIN + 1) * (2 * WIN + 1); c += 64) {
        const int dy = c / 11 - WIN;
        const int dx = c % 11 - WIN;
        const int y = cy + dy, x = cx + dx;
        if (y >= 0 && y < HH && x >= 0 && x < WW) {
            const float v = resp[(size_t)b * NPB + (size_t)y * WW + (size_t)x];
            if (v > 0.f) { wsum += (double)v; wss += (double)v * (double)v; wcnt += 1u; }
        }
    }
    for (int off = 32; off > 0; off >>= 1) {
        wsum += __shfl_down(wsum, off, 64);
        wss  += __shfl_down(wss,  off, 64);
        wcnt += __shfl_down(wcnt, off, 64);
    }

    __shared__ float spsr[BB];
    if (lane == 0) {
        const double S  = ds  - wsum;
        const double SS = dss - wss;
        const double N  = (double)(cnt - wcnt);
        const double mean = S / N;
        const double var  = (SS - N * mean * mean) / (N - 1.0);
        const double sd   = sqrt(var);
        spsr[b] = (float)(((double)bv - mean) / (sd + 1e-5));
    }
    __syncthreads();

    if (t == 0) {
        // same pairwise order as the old shuffle tree: ((0+4)+(2+6)) + ((1+5)+(3+7))
        const float w0 = spsr[0] + spsr[4];
        const float w1 = spsr[1] + spsr[5];
        const float w2 = spsr[2] + spsr[6];
        const float w3 = spsr[3] + spsr[7];
        const float u0 = w0 + w2;
        const float u1 = w1 + w3;
        out[0] = (u0 + u1) * (1.0f / BB);
    }
}

extern "C" void kernel_launch(void* const* d_in, const int* in_sizes, int n_in,
                              void* d_out, int out_size, void* d_ws, size_t ws_size,
                              hipStream_t stream) {
    const float* resp = (const float*)d_in[0];
    float* out = (float*)d_out;

    char* ws = (char*)d_ws;
    // layout: [dS: 2048 dbl][dSS: 2048 dbl][fM: 2048 f32][uI: 2048 u32][uC: 2048 u32]
    double*   dS  = (double*)(ws);
    double*   dSS = (double*)(ws + 16384);
    float*    fM  = (float*)(ws + 32768);
    unsigned* uI  = (unsigned*)(ws + 40960);
    unsigned* uC  = (unsigned*)(ws + 49152);

    dim3 g1(NBLK, BB);
    psr_pass1<<<g1, TPB, 0, stream>>>(resp, dS, dSS, fM, uI, uC);
    psr_pass2<<<1, 512, 0, stream>>>(resp, dS, dSS, fM, uI, uC, out);
}